// Round 8
// baseline (2900.020 us; speedup 1.0000x reference)
//
#include <hip/hip_runtime.h>
#include <cstdint>
#include <cstddef>

#define GRID_DIM 160
#define GRID_VOX (GRID_DIM * GRID_DIM * GRID_DIM)
#define CIN 64
#define COUT 96
#define NK 27
#define NSIDE 26
#define CAP_SIDE 65536          // capacity per side-offset pair list (measured ~16k)
#define PAIRS_PER_BLOCK 64
#define CURS_STRIDE 16          // cursors 64B apart -> no same-line atomic contention

// ---------------------------------------------------------------------------
// K1: scatter point indices into dense voxel grid. Grid pre-memset to -1.
// atomicMax = last-update-wins (matches numpy scatter order), verified R1.
// ---------------------------------------------------------------------------
__global__ __launch_bounds__(256) void scatter_kernel(
    const int* __restrict__ coords, int* __restrict__ grid, int N)
{
    int i = blockIdx.x * 256 + threadIdx.x;
    if (i >= N) return;
    int lin = (coords[i * 3] * GRID_DIM + coords[i * 3 + 1]) * GRID_DIM
            + coords[i * 3 + 2];
    atomicMax(&grid[lin], i);
}

// ---------------------------------------------------------------------------
// K2: repack weight [27][64][96] -> [27][16][96][4] (wt2[k][ci4][c][j]).
// ---------------------------------------------------------------------------
__global__ __launch_bounds__(256) void repack_w(
    const float* __restrict__ w, float* __restrict__ wt2)
{
    int idx = blockIdx.x * 256 + threadIdx.x;
    if (idx >= NK * CIN * COUT) return;
    int k   = idx / (CIN * COUT);
    int r   = idx - k * (CIN * COUT);
    int ci  = r / COUT;
    int c   = r - ci * COUT;
    wt2[(((size_t)k * 16 + (ci >> 2)) * COUT + c) * 4 + (ci & 3)] = w[idx];
}

// ---------------------------------------------------------------------------
// K3: build rulebook with mirror symmetry + forced probe MLP (unchanged R4).
// ---------------------------------------------------------------------------
__global__ __launch_bounds__(256, 4) void fill_pairs(
    const int* __restrict__ coords, const int* __restrict__ grid,
    int* __restrict__ cursors, int2* __restrict__ pairs,
    int* __restrict__ winner, int N)
{
    int p = blockIdx.x * 256 + threadIdx.x;
    if (p >= N) return;
    int lane = threadIdx.x & 63;

    int c0 = coords[p * 3], c1 = coords[p * 3 + 1], c2 = coords[p * 3 + 2];
    int ownLin = (c0 * GRID_DIM + c1) * GRID_DIM + c2;

    int nidx[13];
    #pragma unroll
    for (int k = 0; k < 13; ++k) {
        int dz = k / 9 - 1, dy = (k / 3) % 3 - 1, dx = k % 3 - 1;
        int a0 = c0 + dz, a1 = c1 + dy, a2 = c2 + dx;
        bool v = ((unsigned)a0 < GRID_DIM) & ((unsigned)a1 < GRID_DIM) &
                 ((unsigned)a2 < GRID_DIM);
        int lin = v ? (a0 * GRID_DIM + a1) * GRID_DIM + a2 : ownLin;
        int g = grid[lin];
        nidx[k] = v ? g : -1;
    }
    int w = grid[ownLin];

    int chk = w;
    #pragma unroll
    for (int k = 0; k < 13; ++k) chk += nidx[k];
    asm volatile("" :: "v"(chk));

    winner[p] = w;
    bool isW = (w == p);

    #pragma unroll
    for (int k = 0; k < 13; ++k) {
        int q = nidx[k];
        bool valid = q >= 0;

        unsigned long long m1 = __ballot(valid);
        if (m1) {
            int leader = __ffsll((long long)m1) - 1;
            int cnt    = __popcll(m1);
            int off    = __popcll(m1 & ((1ull << lane) - 1ull));
            int base = 0;
            if (lane == leader) base = atomicAdd(&cursors[k * CURS_STRIDE], cnt);
            base = __shfl(base, leader);
            int slot = base + off;
            if (valid && slot < CAP_SIDE)
                pairs[(size_t)k * CAP_SIDE + slot] = make_int2(q, p);
        }

        bool mv = valid && isW;
        unsigned long long m2 = __ballot(mv);
        if (m2) {
            int leader = __ffsll((long long)m2) - 1;
            int cnt    = __popcll(m2);
            int off    = __popcll(m2 & ((1ull << lane) - 1ull));
            int base = 0;
            if (lane == leader) base = atomicAdd(&cursors[(25 - k) * CURS_STRIDE], cnt);
            base = __shfl(base, leader);
            int slot = base + off;
            if (mv && slot < CAP_SIDE)
                pairs[(size_t)(25 - k) * CAP_SIDE + slot] = make_int2(w, q);
        }
    }
}

// ---------------------------------------------------------------------------
// K4: side-offset gather-GEMM-scatter, 2-pair register tile per half-wave.
// LDS traffic /2 vs the 1-pair version; __launch_bounds__(256,4) caps VGPR
// at 128 so the compiler can't hoist the whole feature stream (R7 lesson:
// 4-pair tile -> 224 VGPR -> 11% occupancy -> regression).
// ---------------------------------------------------------------------------
__global__ __launch_bounds__(256, 4) void conv_side(
    const float* __restrict__ feat, const float* __restrict__ wt2,
    const int* __restrict__ cursors, const int2* __restrict__ pairs,
    float* __restrict__ out)
{
    int si = blockIdx.y;                    // 0..25
    int k  = (si < 13) ? si : si + 1;       // weight index (skip center 13)
    int cnt = cursors[si * CURS_STRIDE];
    if (cnt > CAP_SIDE) cnt = CAP_SIDE;
    int base = blockIdx.x * PAIRS_PER_BLOCK;
    if (base >= cnt) return;                // uniform early-exit (before barrier)

    __shared__ float4 wlds[16 * COUT];      // 24576 B
    {
        const float4* src = (const float4*)(wt2 + (size_t)k * 16 * COUT * 4);
        for (int i = threadIdx.x; i < 16 * COUT; i += 256) wlds[i] = src[i];
    }
    __syncthreads();

    int hw = threadIdx.x >> 5;              // half-wave 0..7
    int h  = threadIdx.x & 31;
    const int2* seg = pairs + (size_t)si * CAP_SIDE;

    #pragma unroll
    for (int g = 0; g < 4; ++g) {           // 4 groups of 16 pairs per block
        int idx0 = base + g * 16 + hw * 2;  // this half-wave's 2 pairs
        if (idx0 >= cnt) continue;          // half-wave-uniform
        int nv = cnt - idx0; if (nv > 2) nv = 2;

        int2 pr0 = seg[idx0];
        int2 pr1 = seg[(nv > 1) ? idx0 + 1 : idx0];    // pad re-reads idx0

        const float4* fp0 = (const float4*)(feat + (size_t)pr0.x * CIN);
        const float4* fp1 = (const float4*)(feat + (size_t)pr1.x * CIN);

        float a00 = 0.f, a01 = 0.f, a02 = 0.f;
        float a10 = 0.f, a11 = 0.f, a12 = 0.f;

        #pragma unroll
        for (int ci4 = 0; ci4 < 16; ++ci4) {
            const float4* wv = &wlds[ci4 * COUT];
            float4 wa = wv[h], wb = wv[h + 32], wc = wv[h + 64];
            float4 f0 = fp0[ci4];
            float4 f1 = fp1[ci4];
            a00 = fmaf(f0.w, wa.w, fmaf(f0.z, wa.z, fmaf(f0.y, wa.y, fmaf(f0.x, wa.x, a00))));
            a01 = fmaf(f0.w, wb.w, fmaf(f0.z, wb.z, fmaf(f0.y, wb.y, fmaf(f0.x, wb.x, a01))));
            a02 = fmaf(f0.w, wc.w, fmaf(f0.z, wc.z, fmaf(f0.y, wc.y, fmaf(f0.x, wc.x, a02))));
            a10 = fmaf(f1.w, wa.w, fmaf(f1.z, wa.z, fmaf(f1.y, wa.y, fmaf(f1.x, wa.x, a10))));
            a11 = fmaf(f1.w, wb.w, fmaf(f1.z, wb.z, fmaf(f1.y, wb.y, fmaf(f1.x, wb.x, a11))));
            a12 = fmaf(f1.w, wc.w, fmaf(f1.z, wc.z, fmaf(f1.y, wc.y, fmaf(f1.x, wc.x, a12))));
        }

        float* op0 = out + (size_t)pr0.y * COUT;
        atomicAdd(op0 + h,      a00);
        atomicAdd(op0 + h + 32, a01);
        atomicAdd(op0 + h + 64, a02);
        if (nv > 1) {
            float* op1 = out + (size_t)pr1.y * COUT;
            atomicAdd(op1 + h,      a10);
            atomicAdd(op1 + h + 32, a11);
            atomicAdd(op1 + h + 64, a12);
        }
    }
}

// ---------------------------------------------------------------------------
// K5: center + bias + LayerNorm + ReLU, 2-point register tile per half-wave,
// VGPR-capped (same R7 lesson). Winners only; losers fixed by dup_fix.
// ---------------------------------------------------------------------------
__global__ __launch_bounds__(256, 4) void center_ln_relu(
    const float* __restrict__ feat, const int* __restrict__ winner,
    const float* __restrict__ wt2,
    const float* __restrict__ bias, const float* __restrict__ gamma,
    const float* __restrict__ beta, float* __restrict__ out, int N)
{
    __shared__ float4 wlds[16 * COUT];
    {
        const float4* src = (const float4*)(wt2 + (size_t)13 * 16 * COUT * 4);
        for (int i = threadIdx.x; i < 16 * COUT; i += 256) wlds[i] = src[i];
    }
    __syncthreads();

    int hw = threadIdx.x >> 5;
    int h  = threadIdx.x & 31;
    float b0 = bias[h], b1 = bias[h + 32], b2 = bias[h + 64];
    float g0 = gamma[h], g1 = gamma[h + 32], g2 = gamma[h + 64];
    float e0 = beta[h],  e1 = beta[h + 32],  e2 = beta[h + 64];

    int pb = blockIdx.x * 128 + hw * 16;    // 16 points per half-wave

    #pragma unroll
    for (int j = 0; j < 8; ++j) {           // 8 tiles of 2 points
        int p0 = pb + j * 2;
        if (p0 >= N) break;

        int pA = p0, pB = min(p0 + 1, N - 1);
        int wnA = winner[pA];
        int wnB = (p0 + 1 < N) ? winner[pB] : -1;
        const float4* fpA = (const float4*)(feat + (size_t)pA * CIN);
        const float4* fpB = (const float4*)(feat + (size_t)pB * CIN);
        float* opA = out + (size_t)pA * COUT;
        float* opB = out + (size_t)pB * COUT;

        float a00 = opA[h] + b0, a01 = opA[h + 32] + b1, a02 = opA[h + 64] + b2;
        float a10 = opB[h] + b0, a11 = opB[h + 32] + b1, a12 = opB[h + 64] + b2;

        #pragma unroll
        for (int ci4 = 0; ci4 < 16; ++ci4) {
            const float4* wv = &wlds[ci4 * COUT];
            float4 wa = wv[h], wb = wv[h + 32], wc = wv[h + 64];
            float4 f0 = fpA[ci4];
            float4 f1 = fpB[ci4];
            a00 = fmaf(f0.w, wa.w, fmaf(f0.z, wa.z, fmaf(f0.y, wa.y, fmaf(f0.x, wa.x, a00))));
            a01 = fmaf(f0.w, wb.w, fmaf(f0.z, wb.z, fmaf(f0.y, wb.y, fmaf(f0.x, wb.x, a01))));
            a02 = fmaf(f0.w, wc.w, fmaf(f0.z, wc.z, fmaf(f0.y, wc.y, fmaf(f0.x, wc.x, a02))));
            a10 = fmaf(f1.w, wa.w, fmaf(f1.z, wa.z, fmaf(f1.y, wa.y, fmaf(f1.x, wa.x, a10))));
            a11 = fmaf(f1.w, wb.w, fmaf(f1.z, wb.z, fmaf(f1.y, wb.y, fmaf(f1.x, wb.x, a11))));
            a12 = fmaf(f1.w, wc.w, fmaf(f1.z, wc.z, fmaf(f1.y, wc.y, fmaf(f1.x, wc.x, a12))));
        }

        // LN for point A
        {
            float s  = a00 + a01 + a02;
            float s2 = a00 * a00 + a01 * a01 + a02 * a02;
            #pragma unroll
            for (int off = 16; off >= 1; off >>= 1) {
                s  += __shfl_xor(s, off);
                s2 += __shfl_xor(s2, off);
            }
            float mu  = s * (1.0f / COUT);
            float var = s2 * (1.0f / COUT) - mu * mu;
            float rs  = rsqrtf(var + 1e-5f);
            float o0 = (a00 - mu) * rs * g0 + e0;
            float o1 = (a01 - mu) * rs * g1 + e1;
            float o2 = (a02 - mu) * rs * g2 + e2;
            if (wnA == pA) {
                opA[h]      = o0 > 0.f ? o0 : 0.f;
                opA[h + 32] = o1 > 0.f ? o1 : 0.f;
                opA[h + 64] = o2 > 0.f ? o2 : 0.f;
            }
        }
        // LN for point B
        {
            float s  = a10 + a11 + a12;
            float s2 = a10 * a10 + a11 * a11 + a12 * a12;
            #pragma unroll
            for (int off = 16; off >= 1; off >>= 1) {
                s  += __shfl_xor(s, off);
                s2 += __shfl_xor(s2, off);
            }
            float mu  = s * (1.0f / COUT);
            float var = s2 * (1.0f / COUT) - mu * mu;
            float rs  = rsqrtf(var + 1e-5f);
            float o0 = (a10 - mu) * rs * g0 + e0;
            float o1 = (a11 - mu) * rs * g1 + e1;
            float o2 = (a12 - mu) * rs * g2 + e2;
            if (p0 + 1 < N && wnB == pB) {
                opB[h]      = o0 > 0.f ? o0 : 0.f;
                opB[h + 32] = o1 > 0.f ? o1 : 0.f;
                opB[h + 64] = o2 > 0.f ? o2 : 0.f;
            }
        }
    }
}

// ---------------------------------------------------------------------------
// K6: duplicate-coordinate fixup — losers copy the winner's final row.
// ---------------------------------------------------------------------------
__global__ __launch_bounds__(256) void dup_fix(
    const int* __restrict__ winner, float* __restrict__ out, int N)
{
    int p = blockIdx.x * 8 + (threadIdx.x >> 5);
    if (p >= N) return;
    int w = winner[p];
    if (w == p) return;
    int h = threadIdx.x & 31;
    out[(size_t)p * COUT + h]      = out[(size_t)w * COUT + h];
    out[(size_t)p * COUT + h + 32] = out[(size_t)w * COUT + h + 32];
    out[(size_t)p * COUT + h + 64] = out[(size_t)w * COUT + h + 64];
}

// ---------------------------------------------------------------------------
extern "C" void kernel_launch(void* const* d_in, const int* in_sizes, int n_in,
                              void* d_out, int out_size, void* d_ws, size_t ws_size,
                              hipStream_t stream)
{
    const float* feat   = (const float*)d_in[0];
    const int*   coords = (const int*)d_in[1];
    const float* weight = (const float*)d_in[2];
    const float* bias   = (const float*)d_in[3];
    const float* gamma  = (const float*)d_in[4];
    const float* beta   = (const float*)d_in[5];
    float* out = (float*)d_out;

    int N = in_sizes[0] / CIN;   // 262144

    char* wsp = (char*)d_ws;
    int*   grid_ws = (int*)wsp;                       wsp += (size_t)GRID_VOX * 4;
    float* wt2     = (float*)wsp;                     wsp += (size_t)NK * CIN * COUT * 4;
    int*   cursors = (int*)wsp;                       wsp += (size_t)NSIDE * CURS_STRIDE * 4;
    int*   winner  = (int*)wsp;                       wsp += (size_t)N * 4;
    int2*  pairs   = (int2*)wsp;

    hipMemsetAsync(grid_ws, 0xFF, (size_t)GRID_VOX * 4, stream);
    hipMemsetAsync(cursors, 0, (size_t)NSIDE * CURS_STRIDE * 4, stream);
    hipMemsetAsync(out, 0, (size_t)N * COUT * 4, stream);

    scatter_kernel<<<(N + 255) / 256, 256, 0, stream>>>(coords, grid_ws, N);
    repack_w<<<(NK * CIN * COUT + 255) / 256, 256, 0, stream>>>(weight, wt2);
    fill_pairs<<<(N + 255) / 256, 256, 0, stream>>>(coords, grid_ws, cursors,
                                                    pairs, winner, N);

    dim3 gside(CAP_SIDE / PAIRS_PER_BLOCK, 26);       // early-exit tail
    conv_side<<<gside, 256, 0, stream>>>(feat, wt2, cursors, pairs, out);

    center_ln_relu<<<(N + 127) / 128, 256, 0, stream>>>(
        feat, winner, wt2, bias, gamma, beta, out, N);

    dup_fix<<<(N + 7) / 8, 256, 0, stream>>>(winner, out, N);
}